// Round 1
// baseline (3327.951 us; speedup 1.0000x reference)
//
#include <hip/hip_runtime.h>
#include <math.h>

#define B_ 32
#define SSRC 512
#define D_ 512
#define STRIDE_ 4
#define V_ 512
#define L_ 256
#define T_ (SSRC * STRIDE_)   // 2048
#define S_ (2 * L_ + 1)       // 513

static __device__ __constant__ const float NEGF = -1e30f;

// ---------------------------------------------------------------------------
// Generic tiled fp32 GEMM: C[M,N] = op(A[M,K] @ B[K,N] + bias)
// BM=BN=128, BK=8, 256 threads, each thread 8x8.
// Requires M%128==0, N%128==0, K%8==0 (true for all our shapes).
// ---------------------------------------------------------------------------
template <bool RELU, bool BIAS>
__global__ __launch_bounds__(256) void gemm_f32(
    const float* __restrict__ A, int lda,
    const float* __restrict__ Bm, int ldb,
    float* __restrict__ C, int ldc,
    const float* __restrict__ bias, int K)
{
    constexpr int BM = 128, BN = 128, BK = 8;
    __shared__ float As[BK][BM];
    __shared__ float Bs[BK][BN];

    const int tid = threadIdx.x;
    const long bm = (long)blockIdx.y * BM;
    const long bn = (long)blockIdx.x * BN;
    const int tx = tid & 15;   // 16 col-groups
    const int ty = tid >> 4;   // 16 row-groups

    float acc[8][8] = {};

    // A tile load: 128x8 floats, one float4 per thread
    const int arow = tid >> 1;
    const int acol = (tid & 1) << 2;
    // B tile load: 8x128 floats, one float4 per thread
    const int brow = tid >> 5;
    const int bcol = (tid & 31) << 2;

    const float* Ap = A + (bm + arow) * (long)lda + acol;
    const float* Bp = Bm + (long)brow * ldb + bn + bcol;

    for (int k0 = 0; k0 < K; k0 += BK) {
        float4 av = *(const float4*)Ap;
        float4 bv = *(const float4*)Bp;
        __syncthreads();   // previous iteration's reads complete
        As[acol + 0][arow] = av.x;
        As[acol + 1][arow] = av.y;
        As[acol + 2][arow] = av.z;
        As[acol + 3][arow] = av.w;
        *(float4*)&Bs[brow][bcol] = bv;
        __syncthreads();
        Ap += BK;
        Bp += (long)BK * ldb;
#pragma unroll
        for (int k = 0; k < BK; ++k) {
            float a[8], b[8];
            *(float4*)&a[0] = *(const float4*)&As[k][ty * 8];
            *(float4*)&a[4] = *(const float4*)&As[k][ty * 8 + 4];
            *(float4*)&b[0] = *(const float4*)&Bs[k][tx * 4];
            *(float4*)&b[4] = *(const float4*)&Bs[k][tx * 4 + 64];
#pragma unroll
            for (int i = 0; i < 8; ++i)
#pragma unroll
                for (int j = 0; j < 8; ++j)
                    acc[i][j] = fmaf(a[i], b[j], acc[i][j]);
        }
    }

    float bv[8] = {};
    if (BIAS) {
#pragma unroll
        for (int j = 0; j < 4; ++j) {
            bv[j]     = bias[bn + tx * 4 + j];
            bv[4 + j] = bias[bn + 64 + tx * 4 + j];
        }
    }
#pragma unroll
    for (int i = 0; i < 8; ++i) {
        long row = bm + ty * 8 + i;
        float* crow = C + row * (long)ldc + bn;
        float o[8];
#pragma unroll
        for (int j = 0; j < 8; ++j) {
            float x = acc[i][j];
            if (BIAS) x += bv[j];
            if (RELU) x = fmaxf(x, 0.f);
            o[j] = x;
        }
        *(float4*)&crow[tx * 4]      = make_float4(o[0], o[1], o[2], o[3]);
        *(float4*)&crow[64 + tx * 4] = make_float4(o[4], o[5], o[6], o[7]);
    }
}

// ---------------------------------------------------------------------------
// bc[k*1024+h] = b1[h] + sum_d b_exp[k*512+d] * W1[d,h]
// ---------------------------------------------------------------------------
__global__ __launch_bounds__(256) void combine_bias(
    const float* __restrict__ b_exp, const float* __restrict__ W1,
    const float* __restrict__ b1, float* __restrict__ bc)
{
    int j = blockIdx.x * 256 + threadIdx.x;   // < 4096
    int k = j >> 10, h = j & 1023;
    float s = b1[h];
    const float* be = b_exp + k * 512;
    for (int d = 0; d < 512; ++d)
        s = fmaf(be[d], W1[d * 1024 + h], s);
    bc[j] = s;
}

// ---------------------------------------------------------------------------
// In-place log_softmax over rows of 512 floats. One block (256 thr) per row.
// ---------------------------------------------------------------------------
__global__ __launch_bounds__(256) void logsoftmax_rows(float* __restrict__ x)
{
    long row = blockIdx.x;
    float* p = x + row * 512;
    int tid = threadIdx.x;
    float2 v = *(float2*)&p[tid * 2];
    float m = fmaxf(v.x, v.y);
#pragma unroll
    for (int off = 32; off; off >>= 1) m = fmaxf(m, __shfl_xor(m, off));
    __shared__ float redm[4], reds[4];
    if ((tid & 63) == 0) redm[tid >> 6] = m;
    __syncthreads();
    m = fmaxf(fmaxf(redm[0], redm[1]), fmaxf(redm[2], redm[3]));
    float s = expf(v.x - m) + expf(v.y - m);
#pragma unroll
    for (int off = 32; off; off >>= 1) s += __shfl_xor(s, off);
    if ((tid & 63) == 0) reds[tid >> 6] = s;
    __syncthreads();
    s = (reds[0] + reds[1]) + (reds[2] + reds[3]);
    float lse = m + logf(s);
    float2 o;
    o.x = v.x - lse;
    o.y = v.y - lse;
    *(float2*)&p[tid * 2] = o;
}

// ---------------------------------------------------------------------------
// CTC forward DP. One block per batch sample, 576 threads (S=513 states).
// ---------------------------------------------------------------------------
__device__ __forceinline__ int block_sum_int(int v, int* sred, int tid)
{
#pragma unroll
    for (int off = 32; off; off >>= 1) v += __shfl_down(v, off);
    int wid = tid >> 6;
    if ((tid & 63) == 0) sred[wid] = v;
    __syncthreads();
    int s = 0;
#pragma unroll
    for (int w = 0; w < 9; ++w) s += sred[w];
    __syncthreads();
    return s;
}

__global__ __launch_bounds__(576) void ctc_dp(
    const float* __restrict__ lp,        // [B,T,V] logprobs
    const int* __restrict__ enc_mask,    // [B,SSRC]
    const int* __restrict__ targets,     // [B,L]
    const int* __restrict__ tgt_mask,    // [B,L]
    float* __restrict__ out_len_f,       // [B] (float values)
    float* __restrict__ per_sample,      // [B] ws
    int* __restrict__ tl_out)            // [B] ws
{
    const int b = blockIdx.x;
    const int tid = threadIdx.x;
    __shared__ float abuf[2][S_];
    __shared__ int sred[9];

    int v = 0;
    if (tid < SSRC) v = (enc_mask[b * SSRC + tid] != 0) ? 1 : 0;
    int slen = block_sum_int(v, sred, tid);
    v = 0;
    if (tid < L_) v = (tgt_mask[b * L_ + tid] != 0) ? 1 : 0;
    int tl = block_sum_int(v, sred, tid);

    const int input_len = STRIDE_ * slen;

    // extended labels & skip flags (per thread)
    int e = 1;     // BLANK
    bool skip = false;
    if (tid < S_ && (tid & 1)) {
        e = targets[b * L_ + (tid >> 1)];
        int eprev = (tid >= 3) ? targets[b * L_ + (tid >> 1) - 1] : 1;
        skip = (e != 1) && (e != eprev);
    }

    const float* lpb = lp + (long)b * T_ * V_;

    if (tid < S_) {
        float a0 = NEGF;
        if (tid == 0) a0 = lpb[1];                      // blank
        else if (tid == 1 && tl > 0) a0 = lpb[e];
        abuf[0][tid] = a0;
    }
    __syncthreads();

    // prefetch lp for t=1
    float lp_cur = 0.f;
    if (tid < S_) lp_cur = lpb[(long)V_ + e];

    int cur = 0;
    for (int t = 1; t < T_; ++t) {
        float lp_next = 0.f;
        if (tid < S_ && t + 1 < T_) lp_next = lpb[(long)(t + 1) * V_ + e];
        float newv = 0.f;
        if (tid < S_) {
            float a0 = abuf[cur][tid];
            float a1 = (tid >= 1) ? abuf[cur][tid - 1] : NEGF;
            float a2 = (skip && tid >= 2) ? abuf[cur][tid - 2] : NEGF;
            float m = fmaxf(a0, fmaxf(a1, a2));
            float lse = m + logf(expf(a0 - m) + expf(a1 - m) + expf(a2 - m));
            newv = (t < input_len) ? (lse + lp_cur) : a0;
        }
        if (tid < S_) abuf[cur ^ 1][tid] = newv;
        __syncthreads();
        cur ^= 1;
        lp_cur = lp_next;
    }

    if (tid == 0) {
        int il = 2 * tl;
        float al = abuf[cur][il];
        float ap = (tl > 0 && il >= 1) ? abuf[cur][il - 1] : NEGF;
        float m = fmaxf(al, ap);
        float ps = -(m + log1pf(expf(fminf(al, ap) - m)));
        per_sample[b] = ps;
        tl_out[b] = tl;
        out_len_f[b] = (float)(STRIDE_ * slen);
    }
}

__global__ __launch_bounds__(64) void ctc_loss_final(
    const float* __restrict__ per_sample, const int* __restrict__ tl,
    float* __restrict__ out_loss)
{
    int tid = threadIdx.x;
    float v = 0.f;
    if (tid < B_) {
        int t = tl[tid] < 1 ? 1 : tl[tid];
        v = per_sample[tid] / (float)t;
    }
#pragma unroll
    for (int off = 32; off; off >>= 1) v += __shfl_down(v, off);
    if (tid == 0) {
        float loss = v / (float)B_;
        if (isnan(loss) || isinf(loss)) loss = 0.f;
        *out_loss = loss;
    }
}

// ---------------------------------------------------------------------------
extern "C" void kernel_launch(void* const* d_in, const int* in_sizes, int n_in,
                              void* d_out, int out_size, void* d_ws, size_t ws_size,
                              hipStream_t stream)
{
    (void)in_sizes; (void)n_in; (void)out_size; (void)ws_size;

    const float* rep      = (const float*)d_in[0];
    const int*   enc_mask = (const int*)d_in[1];
    const int*   targets  = (const int*)d_in[2];
    const int*   tgt_mask = (const int*)d_in[3];
    const float* W_exp    = (const float*)d_in[4];
    const float* b_exp    = (const float*)d_in[5];
    const float* W1       = (const float*)d_in[6];
    const float* b1       = (const float*)d_in[7];
    const float* W2       = (const float*)d_in[8];
    const float* b2       = (const float*)d_in[9];

    float* out       = (float*)d_out;
    float* logprobs  = out;                                   // B*T*V
    float* out_len_f = out + (size_t)B_ * T_ * V_;            // B
    float* out_loss  = out_len_f + B_;                        // 1

    float* Wc = (float*)d_ws;                                 // 512*4096
    float* bc = Wc + (size_t)512 * 4096;                      // 4096
    float* Hc = bc + 4096;                                    // 2048*4096 (chunk)
    float* per_sample = Hc + (size_t)2048 * 4096;             // B
    int*   tl_out = (int*)(per_sample + B_);                  // B

    // 1) combined weights: Wc[e, k*1024+h] = sum_d W_exp[e, k*512+d] * W1[d,h]
    for (int k = 0; k < 4; ++k)
        gemm_f32<false, false><<<dim3(1024 / 128, 512 / 128), 256, 0, stream>>>(
            W_exp + k * 512, 2048, W1, 1024, Wc + k * 1024, 4096, nullptr, 512);
    combine_bias<<<16, 256, 0, stream>>>(b_exp, W1, b1, bc);

    // 2) 8 chunks: H = relu(rep @ Wc + bc) ; logits = H @ W2 + b2 -> d_out
    for (int c = 0; c < 8; ++c) {
        const float* Arep = rep + (size_t)c * 2048 * 512;
        gemm_f32<true, true><<<dim3(4096 / 128, 2048 / 128), 256, 0, stream>>>(
            Arep, 512, Wc, 4096, Hc, 4096, bc, 512);
        gemm_f32<false, true><<<dim3(512 / 128, 8192 / 128), 256, 0, stream>>>(
            Hc, 1024, W2, 512, logprobs + (size_t)c * 8192 * 512, 512, b2, 1024);
    }

    // 3) in-place log_softmax over rows of 512
    logsoftmax_rows<<<B_ * T_, 256, 0, stream>>>(logprobs);

    // 4) CTC forward DP + loss
    ctc_dp<<<B_, 576, 0, stream>>>(logprobs, enc_mask, targets, tgt_mask,
                                   out_len_f, per_sample, tl_out);
    ctc_loss_final<<<1, 64, 0, stream>>>(per_sample, tl_out, out_loss);
}

// Round 2
// 1654.425 us; speedup vs baseline: 2.0115x; 2.0115x over previous
//
#include <hip/hip_runtime.h>
#include <math.h>

#define B_ 32
#define SSRC 512
#define D_ 512
#define STRIDE_ 4
#define V_ 512
#define L_ 256
#define T_ (SSRC * STRIDE_)   // 2048
#define S_ (2 * L_ + 1)       // 513
#define BLANKI 1

typedef __attribute__((ext_vector_type(8))) short bf16x8;
typedef __attribute__((ext_vector_type(4))) float f32x4;

__device__ __forceinline__ unsigned short bf16r(float x) {
    unsigned u = __float_as_uint(x);
    return (unsigned short)((u + 0x7fffu + ((u >> 16) & 1u)) >> 16);
}

__device__ __forceinline__ void gl_lds16(const unsigned short* g, unsigned short* l) {
    __builtin_amdgcn_global_load_lds(
        (const __attribute__((address_space(1))) unsigned int*)g,
        (__attribute__((address_space(3))) unsigned int*)l, 16, 0, 0);
}

// ---------------------------------------------------------------------------
// fp32 tiled GEMM (small Wc precompute only). BM=BN=128, BK=8, 256 thr.
// ---------------------------------------------------------------------------
template <bool RELU, bool BIAS>
__global__ __launch_bounds__(256) void gemm_f32(
    const float* __restrict__ A, int lda,
    const float* __restrict__ Bm, int ldb,
    float* __restrict__ C, int ldc,
    const float* __restrict__ bias, int K)
{
    constexpr int BK = 8;
    __shared__ float As[BK][128];
    __shared__ float Bs[BK][128];
    const int tid = threadIdx.x;
    const long bm = (long)blockIdx.y * 128;
    const long bn = (long)blockIdx.x * 128;
    const int tx = tid & 15, ty = tid >> 4;
    float acc[8][8] = {};
    const int arow = tid >> 1, acol = (tid & 1) << 2;
    const int brow = tid >> 5, bcol = (tid & 31) << 2;
    const float* Ap = A + (bm + arow) * (long)lda + acol;
    const float* Bp = Bm + (long)brow * ldb + bn + bcol;
    for (int k0 = 0; k0 < K; k0 += BK) {
        float4 av = *(const float4*)Ap;
        float4 bv = *(const float4*)Bp;
        __syncthreads();
        As[acol + 0][arow] = av.x; As[acol + 1][arow] = av.y;
        As[acol + 2][arow] = av.z; As[acol + 3][arow] = av.w;
        *(float4*)&Bs[brow][bcol] = bv;
        __syncthreads();
        Ap += BK; Bp += (long)BK * ldb;
#pragma unroll
        for (int k = 0; k < BK; ++k) {
            float a[8], b[8];
            *(float4*)&a[0] = *(const float4*)&As[k][ty * 8];
            *(float4*)&a[4] = *(const float4*)&As[k][ty * 8 + 4];
            *(float4*)&b[0] = *(const float4*)&Bs[k][tx * 4];
            *(float4*)&b[4] = *(const float4*)&Bs[k][tx * 4 + 64];
#pragma unroll
            for (int i = 0; i < 8; ++i)
#pragma unroll
                for (int j = 0; j < 8; ++j)
                    acc[i][j] = fmaf(a[i], b[j], acc[i][j]);
        }
    }
    float bv[8] = {};
    if (BIAS) {
#pragma unroll
        for (int j = 0; j < 4; ++j) {
            bv[j] = bias[bn + tx * 4 + j];
            bv[4 + j] = bias[bn + 64 + tx * 4 + j];
        }
    }
#pragma unroll
    for (int i = 0; i < 8; ++i) {
        long row = bm + ty * 8 + i;
        float* crow = C + row * (long)ldc + bn;
        float o[8];
#pragma unroll
        for (int j = 0; j < 8; ++j) {
            float x = acc[i][j];
            if (BIAS) x += bv[j];
            if (RELU) x = fmaxf(x, 0.f);
            o[j] = x;
        }
        *(float4*)&crow[tx * 4]      = make_float4(o[0], o[1], o[2], o[3]);
        *(float4*)&crow[64 + tx * 4] = make_float4(o[4], o[5], o[6], o[7]);
    }
}

// ---------------------------------------------------------------------------
// bc[k*1024+h] = b1[h] + sum_d b_exp[k*512+d] * W1[d,h]
// ---------------------------------------------------------------------------
__global__ __launch_bounds__(256) void combine_bias(
    const float* __restrict__ b_exp, const float* __restrict__ W1,
    const float* __restrict__ b1, float* __restrict__ bc)
{
    int j = blockIdx.x * 256 + threadIdx.x;
    int k = j >> 10, h = j & 1023;
    float s = b1[h];
    const float* be = b_exp + k * 512;
    for (int d = 0; d < 512; ++d)
        s = fmaf(be[d], W1[d * 1024 + h], s);
    bc[j] = s;
}

// ---------------------------------------------------------------------------
// fp32 [R,C] -> bf16 transposed [C,R]
// ---------------------------------------------------------------------------
__global__ __launch_bounds__(256) void transpose_cvt(
    const float* __restrict__ in, unsigned short* __restrict__ out, int R, int C)
{
    __shared__ float tile[32][33];
    int bx = blockIdx.x * 32, by = blockIdx.y * 32;
    int tx = threadIdx.x, ty = threadIdx.y;
#pragma unroll
    for (int i = 0; i < 32; i += 8)
        tile[ty + i][tx] = in[(size_t)(by + ty + i) * C + bx + tx];
    __syncthreads();
#pragma unroll
    for (int i = 0; i < 32; i += 8)
        out[(size_t)(bx + ty + i) * R + by + tx] = bf16r(tile[tx][ty + i]);
}

__global__ __launch_bounds__(256) void cvt_f32_bf16(
    const float* __restrict__ in, unsigned short* __restrict__ out, int n4)
{
    int i = blockIdx.x * 256 + threadIdx.x;
    if (i >= n4) return;
    float4 v = ((const float4*)in)[i];
    ushort4 o;
    o.x = bf16r(v.x); o.y = bf16r(v.y); o.z = bf16r(v.z); o.w = bf16r(v.w);
    ((ushort4*)out)[i] = o;
}

// ---------------------------------------------------------------------------
// bf16 MFMA GEMM, m97 structure: 128x128 tile, BK=32, global_load_lds,
// double-buffered LDS, 1 barrier per K-tile. A[M,K], BT[N,K] both bf16
// row-major; C fp32 or bf16 with fp32 bias (+optional relu).
// ---------------------------------------------------------------------------
template <bool RELU, bool OUTBF16>
__global__ __launch_bounds__(256) void gemm_mfma(
    const unsigned short* __restrict__ A, int lda,
    const unsigned short* __restrict__ BT, int ldb,
    void* __restrict__ Cout, int ldc,
    const float* __restrict__ bias, int K)
{
    __shared__ unsigned short As[2][128][32];
    __shared__ unsigned short Bs[2][128][32];
    const int tid = threadIdx.x;
    const int wid = tid >> 6, lane = tid & 63;
    const int bm = blockIdx.y * 128, bn = blockIdx.x * 128;
    const int wm = (wid >> 1) * 64, wn = (wid & 1) * 64;

    f32x4 acc[4][4] = {};

    const int r_in = lane >> 2;          // 0..15 (row within 16-row group)
    const int cch = (lane & 3) * 8;      // bf16 elem offset within row (4x16B)
    const int rbase = wid * 32;

    auto stage = [&](int buf, int k0) {
#pragma unroll
        for (int i = 0; i < 2; ++i) {
            int rloc = rbase + i * 16;
            gl_lds16(A  + (size_t)(bm + rloc + r_in) * lda + k0 + cch, &As[buf][rloc][0]);
            gl_lds16(BT + (size_t)(bn + rloc + r_in) * ldb + k0 + cch, &Bs[buf][rloc][0]);
        }
    };

    const int nt = K / 32;
    stage(0, 0);
    for (int t = 0; t < nt; ++t) {
        int cur = t & 1;
        __syncthreads();                       // drains vmcnt: tile 'cur' ready
        if (t + 1 < nt) stage(cur ^ 1, (t + 1) * 32);
        bf16x8 af[4], bfr[4];
#pragma unroll
        for (int mi = 0; mi < 4; ++mi)
            af[mi] = *(const bf16x8*)&As[cur][wm + mi * 16 + (lane & 15)][(lane >> 4) * 8];
#pragma unroll
        for (int ni = 0; ni < 4; ++ni)
            bfr[ni] = *(const bf16x8*)&Bs[cur][wn + ni * 16 + (lane & 15)][(lane >> 4) * 8];
#pragma unroll
        for (int mi = 0; mi < 4; ++mi)
#pragma unroll
            for (int ni = 0; ni < 4; ++ni)
                acc[mi][ni] = __builtin_amdgcn_mfma_f32_16x16x32_bf16(
                    af[mi], bfr[ni], acc[mi][ni], 0, 0, 0);
    }

    // epilogue: C/D frag layout col=lane&15, row=(lane>>4)*4+q  [m89 verified]
#pragma unroll
    for (int ni = 0; ni < 4; ++ni) {
        int gcol = bn + wn + ni * 16 + (lane & 15);
        float bv = bias[gcol];
#pragma unroll
        for (int mi = 0; mi < 4; ++mi) {
#pragma unroll
            for (int q = 0; q < 4; ++q) {
                int grow = bm + wm + mi * 16 + ((lane >> 4) << 2) + q;
                float x = acc[mi][ni][q] + bv;
                if (RELU) x = fmaxf(x, 0.f);
                if (OUTBF16)
                    ((unsigned short*)Cout)[(size_t)grow * ldc + gcol] = bf16r(x);
                else
                    ((float*)Cout)[(size_t)grow * ldc + gcol] = x;
            }
        }
    }
}

// ---------------------------------------------------------------------------
// In-place log_softmax over rows of 512 floats.
// ---------------------------------------------------------------------------
__global__ __launch_bounds__(256) void logsoftmax_rows(float* __restrict__ x)
{
    long row = blockIdx.x;
    float* p = x + row * 512;
    int tid = threadIdx.x;
    float2 v = *(float2*)&p[tid * 2];
    float m = fmaxf(v.x, v.y);
#pragma unroll
    for (int off = 32; off; off >>= 1) m = fmaxf(m, __shfl_xor(m, off));
    __shared__ float redm[4], reds[4];
    if ((tid & 63) == 0) redm[tid >> 6] = m;
    __syncthreads();
    m = fmaxf(fmaxf(redm[0], redm[1]), fmaxf(redm[2], redm[3]));
    float s = expf(v.x - m) + expf(v.y - m);
#pragma unroll
    for (int off = 32; off; off >>= 1) s += __shfl_xor(s, off);
    if ((tid & 63) == 0) reds[tid >> 6] = s;
    __syncthreads();
    s = (reds[0] + reds[1]) + (reds[2] + reds[3]);
    float lse = m + logf(s);
    float2 o; o.x = v.x - lse; o.y = v.y - lse;
    *(float2*)&p[tid * 2] = o;
}

// ---------------------------------------------------------------------------
// CTC forward DP, probability domain with power-of-2 rescaling.
// 1 wave per sample; lane l owns states 8l..8l+7 (lane 63 also 512).
// ---------------------------------------------------------------------------
struct Raw { float rb, r1, r3, r5, r7; };

__global__ __launch_bounds__(64) void ctc_dp2(
    const float* __restrict__ lp, const int* __restrict__ enc_mask,
    const int* __restrict__ targets, const int* __restrict__ tgt_mask,
    float* __restrict__ out_len_f, float* __restrict__ per_sample,
    int* __restrict__ tl_out)
{
    const int b = blockIdx.x;
    const int l = threadIdx.x;

    int se = 0, st = 0;
    {
        const int* em = enc_mask + (size_t)b * SSRC;
#pragma unroll
        for (int i = 0; i < 8; ++i) se += (em[i * 64 + l] != 0) ? 1 : 0;
        const int* tm = tgt_mask + (size_t)b * L_;
#pragma unroll
        for (int i = 0; i < 4; ++i) st += (tm[i * 64 + l] != 0) ? 1 : 0;
#pragma unroll
        for (int off = 32; off; off >>= 1) {
            se += __shfl_xor(se, off);
            st += __shfl_xor(st, off);
        }
    }
    const int tl = st;
    const int IL = STRIDE_ * se;

    const int4 tg = ((const int4*)(targets + (size_t)b * L_))[l];
    int prevw = __shfl_up(tg.w, 1);
    if (l == 0) prevw = BLANKI;
    const bool k1 = (tg.x != BLANKI) && (tg.x != prevw);
    const bool k3 = (tg.y != BLANKI) && (tg.y != tg.x);
    const bool k5 = (tg.z != BLANKI) && (tg.z != tg.y);
    const bool k7 = (tg.w != BLANKI) && (tg.w != tg.z);

    const float* lpb = lp + (size_t)b * T_ * V_;

    float a0 = 0, a1 = 0, a2 = 0, a3 = 0, a4 = 0, a5 = 0, a6 = 0, a7 = 0, a8 = 0;
    if (l == 0) {
        a0 = expf(lpb[BLANKI]);
        if (tl > 0) a1 = expf(lpb[tg.x]);
    }
    int Ei = 0, pend_e = 0;
    float pend_sc = 1.0f;

    auto load_raw = [&](Raw& r, int t) {
        const float* row = lpb + (size_t)t * V_;
        r.rb = row[BLANKI];
        r.r1 = row[tg.x]; r.r3 = row[tg.y]; r.r5 = row[tg.z]; r.r7 = row[tg.w];
    };

    auto step = [&](const Raw& r) {
        Ei += pend_e;
        const float sc = pend_sc;
        const float C = 1.4426950408889634f;
        float pb = exp2f(r.rb * C) * sc;
        float p1 = exp2f(r.r1 * C) * sc;
        float p3 = exp2f(r.r3 * C) * sc;
        float p5 = exp2f(r.r5 * C) * sc;
        float p7 = exp2f(r.r7 * C) * sc;
        float u1 = __shfl_up(a7, 1);
        float u2 = __shfl_up(a6, 1);
        if (l == 0) { u1 = 0.f; u2 = 0.f; }
        float n0 = (a0 + u1) * pb;
        float n1 = (a1 + a0 + (k1 ? u1 : 0.f)) * p1;
        float n2 = (a2 + a1) * pb;
        float n3 = (a3 + a2 + (k3 ? a1 : 0.f)) * p3;
        float n4 = (a4 + a3) * pb;
        float n5 = (a5 + a4 + (k5 ? a3 : 0.f)) * p5;
        float n6 = (a6 + a5) * pb;
        float n7 = (a7 + a6 + (k7 ? a5 : 0.f)) * p7;
        float n8 = (a8 + a7) * pb;
        float m = fmaxf(fmaxf(fmaxf(n0, n1), fmaxf(n2, n3)),
                        fmaxf(fmaxf(n4, n5), fmaxf(n6, n7)));
        m = fmaxf(m, (l == 63) ? n8 : 0.f);
#pragma unroll
        for (int off = 1; off < 64; off <<= 1) m = fmaxf(m, __shfl_xor(m, off));
        int eb = (int)((__float_as_uint(m) >> 23) & 0xffu) - 127;
        pend_e = eb;
        pend_sc = __uint_as_float((unsigned)(127 - eb) << 23);
        a0 = n0; a1 = n1; a2 = n2; a3 = n3; a4 = n4; a5 = n5; a6 = n6; a7 = n7; a8 = n8;
    };

    const int tmax = IL - 1;
    if (tmax >= 1) {
        Raw rA, rB, rC, rD;
        auto clampt = [&](int t) { return t <= tmax ? t : tmax; };
        load_raw(rA, clampt(1)); load_raw(rB, clampt(2));
        load_raw(rC, clampt(3)); load_raw(rD, clampt(4));
        int t = 1;
        while (t + 3 <= tmax) {
            step(rA); load_raw(rA, clampt(t + 4));
            step(rB); load_raw(rB, clampt(t + 5));
            step(rC); load_raw(rC, clampt(t + 6));
            step(rD); load_raw(rD, clampt(t + 7));
            t += 4;
        }
        if (t <= tmax) { step(rA); ++t; }
        if (t <= tmax) { step(rB); ++t; }
        if (t <= tmax) { step(rC); ++t; }
    }

    __shared__ float as_[S_];
    as_[l * 8 + 0] = a0; as_[l * 8 + 1] = a1; as_[l * 8 + 2] = a2; as_[l * 8 + 3] = a3;
    as_[l * 8 + 4] = a4; as_[l * 8 + 5] = a5; as_[l * 8 + 6] = a6; as_[l * 8 + 7] = a7;
    if (l == 63) as_[512] = a8;
    __syncthreads();
    if (l == 0) {
        int i2 = 2 * tl;
        float al = as_[i2];
        float ap = (tl > 0) ? as_[i2 - 1] : 0.f;
        float s = al + ap;
        per_sample[b] = -(logf(s) + (float)Ei * 0.69314718055994531f);
        tl_out[b] = tl;
        out_len_f[b] = (float)IL;
    }
}

__global__ __launch_bounds__(64) void ctc_loss_final(
    const float* __restrict__ per_sample, const int* __restrict__ tl,
    float* __restrict__ out_loss)
{
    int tid = threadIdx.x;
    float v = 0.f;
    if (tid < B_) {
        int t = tl[tid] < 1 ? 1 : tl[tid];
        v = per_sample[tid] / (float)t;
    }
#pragma unroll
    for (int off = 32; off; off >>= 1) v += __shfl_down(v, off);
    if (tid == 0) {
        float loss = v / (float)B_;
        if (isnan(loss) || isinf(loss)) loss = 0.f;
        *out_loss = loss;
    }
}

// ---------------------------------------------------------------------------
extern "C" void kernel_launch(void* const* d_in, const int* in_sizes, int n_in,
                              void* d_out, int out_size, void* d_ws, size_t ws_size,
                              hipStream_t stream)
{
    (void)in_sizes; (void)n_in; (void)out_size; (void)ws_size;

    const float* rep      = (const float*)d_in[0];
    const int*   enc_mask = (const int*)d_in[1];
    const int*   targets  = (const int*)d_in[2];
    const int*   tgt_mask = (const int*)d_in[3];
    const float* W_exp    = (const float*)d_in[4];
    const float* b_exp    = (const float*)d_in[5];
    const float* W1       = (const float*)d_in[6];
    const float* b1       = (const float*)d_in[7];
    const float* W2       = (const float*)d_in[8];
    const float* b2       = (const float*)d_in[9];

    float* out       = (float*)d_out;
    float* logprobs  = out;                          // B*T*V
    float* out_len_f = out + (size_t)B_ * T_ * V_;   // B
    float* out_loss  = out_len_f + B_;               // 1

    // workspace layout (38.8 MB total; R1 proved >= 42 MB usable)
    unsigned short* WcT  = (unsigned short*)d_ws;                   // [4096][512] bf16
    unsigned short* repb = WcT + (size_t)4096 * 512;                // [16384][512] bf16
    unsigned short* W2T  = repb + (size_t)16384 * 512;              // [512][1024] bf16
    float* bc            = (float*)(W2T + (size_t)512 * 1024);      // [4096] f32
    float* per_sample    = bc + 4096;                               // [64]
    int*   tl_out        = (int*)(per_sample + 64);                 // [64]
    unsigned short* Hc   = (unsigned short*)(tl_out + 64);          // [2048][4096] bf16 chunk
    float* Wc_tmp        = (float*)Hc;                              // [512][4096] f32 (dead before Hc)

    // 1) rep -> bf16
    cvt_f32_bf16<<<8192, 256, 0, stream>>>(rep, repb, (16384 * 512) / 4);

    // 2) folded weights Wc[e, k*1024+h] = sum_d W_exp[e,k*512+d] * W1[d,h]
    for (int k = 0; k < 4; ++k)
        gemm_f32<false, false><<<dim3(8, 4), 256, 0, stream>>>(
            W_exp + k * 512, 2048, W1, 1024, Wc_tmp + k * 1024, 4096, nullptr, 512);
    combine_bias<<<16, 256, 0, stream>>>(b_exp, W1, b1, bc);

    // 3) transposed bf16 weight layouts for MFMA (BT = [N][K])
    transpose_cvt<<<dim3(128, 16), dim3(32, 8), 0, stream>>>(Wc_tmp, WcT, 512, 4096);
    transpose_cvt<<<dim3(16, 32), dim3(32, 8), 0, stream>>>(W2, W2T, 1024, 512);

    // 4) 8 chunks: H = relu(rep@Wc + bc) [bf16]; logits = H@W2 + b2 -> d_out [f32]
    for (int c = 0; c < 8; ++c) {
        gemm_mfma<true, true><<<dim3(32, 16), 256, 0, stream>>>(
            repb + (size_t)c * 2048 * 512, 512, WcT, 512, Hc, 4096, bc, 512);
        gemm_mfma<false, false><<<dim3(4, 64), 256, 0, stream>>>(
            Hc, 1024, W2T, 1024, logprobs + (size_t)c * 8192 * 512, 512, b2, 1024);
    }

    // 5) in-place log_softmax
    logsoftmax_rows<<<B_ * T_, 256, 0, stream>>>(logprobs);

    // 6) CTC DP + loss
    ctc_dp2<<<B_, 64, 0, stream>>>(logprobs, enc_mask, targets, tgt_mask,
                                   out_len_f, per_sample, tl_out);
    ctc_loss_final<<<1, 64, 0, stream>>>(per_sample, tl_out, out_loss);
}

// Round 4
// 886.697 us; speedup vs baseline: 3.7532x; 1.8658x over previous
//
#include <hip/hip_runtime.h>
#include <math.h>

#define B_ 32
#define SSRC 512
#define D_ 512
#define STRIDE_ 4
#define V_ 512
#define L_ 256
#define T_ (SSRC * STRIDE_)   // 2048
#define S_ (2 * L_ + 1)       // 513
#define BLANKI 1
#define PSTRIDE 264           // compact prob row stride (ushorts)
#define BOOST 4096.0f         // 2^12 pre-boost on gathered probs
#define BOOST_BITS 12

typedef __attribute__((ext_vector_type(8))) short bf16x8;
typedef __attribute__((ext_vector_type(4))) float f32x4;

__device__ __forceinline__ unsigned short bf16r(float x) {
    unsigned u = __float_as_uint(x);
    return (unsigned short)((u + 0x7fffu + ((u >> 16) & 1u)) >> 16);
}
__device__ __forceinline__ float bf2f(unsigned short u) {
    return __uint_as_float((unsigned)u << 16);
}
__device__ __forceinline__ void gl_lds16(const unsigned short* g, unsigned short* l) {
    __builtin_amdgcn_global_load_lds(
        (const __attribute__((address_space(1))) unsigned int*)g,
        (__attribute__((address_space(3))) unsigned int*)l, 16, 0, 0);
}

// ---------------------------------------------------------------------------
// fp32 tiled GEMM for the weight fold (gridDim.z slices). BM=BN=128, BK=8.
// ---------------------------------------------------------------------------
__global__ __launch_bounds__(256) void gemm_f32z(
    const float* __restrict__ A, int lda, int zA,
    const float* __restrict__ Bm, int ldb,
    float* __restrict__ C, int ldc, int zC, int K)
{
    constexpr int BK = 8;
    __shared__ float As[BK][128];
    __shared__ float Bs[BK][128];
    A += (size_t)blockIdx.z * zA;
    C += (size_t)blockIdx.z * zC;
    const int tid = threadIdx.x;
    const long bm = (long)blockIdx.y * 128;
    const long bn = (long)blockIdx.x * 128;
    const int tx = tid & 15, ty = tid >> 4;
    float acc[8][8] = {};
    const int arow = tid >> 1, acol = (tid & 1) << 2;
    const int brow = tid >> 5, bcol = (tid & 31) << 2;
    const float* Ap = A + (bm + arow) * (long)lda + acol;
    const float* Bp = Bm + (long)brow * ldb + bn + bcol;
    for (int k0 = 0; k0 < K; k0 += BK) {
        float4 av = *(const float4*)Ap;
        float4 bv = *(const float4*)Bp;
        __syncthreads();
        As[acol + 0][arow] = av.x; As[acol + 1][arow] = av.y;
        As[acol + 2][arow] = av.z; As[acol + 3][arow] = av.w;
        *(float4*)&Bs[brow][bcol] = bv;
        __syncthreads();
        Ap += BK; Bp += (long)BK * ldb;
#pragma unroll
        for (int k = 0; k < BK; ++k) {
            float a[8], b[8];
            *(float4*)&a[0] = *(const float4*)&As[k][ty * 8];
            *(float4*)&a[4] = *(const float4*)&As[k][ty * 8 + 4];
            *(float4*)&b[0] = *(const float4*)&Bs[k][tx * 4];
            *(float4*)&b[4] = *(const float4*)&Bs[k][tx * 4 + 64];
#pragma unroll
            for (int i = 0; i < 8; ++i)
#pragma unroll
                for (int j = 0; j < 8; ++j)
                    acc[i][j] = fmaf(a[i], b[j], acc[i][j]);
        }
    }
#pragma unroll
    for (int i = 0; i < 8; ++i) {
        long row = bm + ty * 8 + i;
        float* crow = C + row * (long)ldc + bn;
        *(float4*)&crow[tx * 4]      = make_float4(acc[i][0], acc[i][1], acc[i][2], acc[i][3]);
        *(float4*)&crow[64 + tx * 4] = make_float4(acc[i][4], acc[i][5], acc[i][6], acc[i][7]);
    }
}

// ---------------------------------------------------------------------------
// bc[k*1024+h] = b1[h] + sum_d b_exp[k*512+d] * W1[d,h]
// ---------------------------------------------------------------------------
__global__ __launch_bounds__(256) void combine_bias(
    const float* __restrict__ b_exp, const float* __restrict__ W1,
    const float* __restrict__ b1, float* __restrict__ bc)
{
    int j = blockIdx.x * 256 + threadIdx.x;
    int k = j >> 10, h = j & 1023;
    float s = b1[h];
    const float* be = b_exp + k * 512;
    for (int d = 0; d < 512; ++d)
        s = fmaf(be[d], W1[d * 1024 + h], s);
    bc[j] = s;
}

// ---------------------------------------------------------------------------
// fp32 [R,C] -> bf16 transposed [C,R]
// ---------------------------------------------------------------------------
__global__ __launch_bounds__(256) void transpose_cvt(
    const float* __restrict__ in, unsigned short* __restrict__ out, int R, int C)
{
    __shared__ float tile[32][33];
    int bx = blockIdx.x * 32, by = blockIdx.y * 32;
    int tx = threadIdx.x, ty = threadIdx.y;
#pragma unroll
    for (int i = 0; i < 32; i += 8)
        tile[ty + i][tx] = in[(size_t)(by + ty + i) * C + bx + tx];
    __syncthreads();
#pragma unroll
    for (int i = 0; i < 32; i += 8)
        out[(size_t)(bx + ty + i) * R + by + tx] = bf16r(tile[tx][ty + i]);
}

__global__ __launch_bounds__(256) void cvt_f32_bf16(
    const float* __restrict__ in, unsigned short* __restrict__ out, int n4)
{
    int i = blockIdx.x * 256 + threadIdx.x;
    if (i >= n4) return;
    float4 v = ((const float4*)in)[i];
    ushort4 o;
    o.x = bf16r(v.x); o.y = bf16r(v.y); o.z = bf16r(v.z); o.w = bf16r(v.w);
    ((ushort4*)out)[i] = o;
}

// ---------------------------------------------------------------------------
// bf16 MFMA GEMM (m97 structure): 128x128 tile, BK=32, global_load_lds,
// double-buffered LDS. A[M,K], BT[N,K] bf16 row-major.
// ---------------------------------------------------------------------------
template <bool RELU, bool OUTBF16>
__global__ __launch_bounds__(256) void gemm_mfma(
    const unsigned short* __restrict__ A, int lda,
    const unsigned short* __restrict__ BT, int ldb,
    void* __restrict__ Cout, int ldc,
    const float* __restrict__ bias, int K)
{
    __shared__ unsigned short As[2][128][32];
    __shared__ unsigned short Bs[2][128][32];
    const int tid = threadIdx.x;
    const int wid = tid >> 6, lane = tid & 63;
    const int bm = blockIdx.y * 128, bn = blockIdx.x * 128;
    const int wm = (wid >> 1) * 64, wn = (wid & 1) * 64;

    f32x4 acc[4][4] = {};
    const int r_in = lane >> 2;
    const int cch = (lane & 3) * 8;
    const int rbase = wid * 32;

    auto stage = [&](int buf, int k0) {
#pragma unroll
        for (int i = 0; i < 2; ++i) {
            int rloc = rbase + i * 16;
            gl_lds16(A  + (size_t)(bm + rloc + r_in) * lda + k0 + cch, &As[buf][rloc][0]);
            gl_lds16(BT + (size_t)(bn + rloc + r_in) * ldb + k0 + cch, &Bs[buf][rloc][0]);
        }
    };

    const int nt = K / 32;
    stage(0, 0);
    for (int t = 0; t < nt; ++t) {
        int cur = t & 1;
        __syncthreads();
        if (t + 1 < nt) stage(cur ^ 1, (t + 1) * 32);
        bf16x8 af[4], bfr[4];
#pragma unroll
        for (int mi = 0; mi < 4; ++mi)
            af[mi] = *(const bf16x8*)&As[cur][wm + mi * 16 + (lane & 15)][(lane >> 4) * 8];
#pragma unroll
        for (int ni = 0; ni < 4; ++ni)
            bfr[ni] = *(const bf16x8*)&Bs[cur][wn + ni * 16 + (lane & 15)][(lane >> 4) * 8];
#pragma unroll
        for (int mi = 0; mi < 4; ++mi)
#pragma unroll
            for (int ni = 0; ni < 4; ++ni)
                acc[mi][ni] = __builtin_amdgcn_mfma_f32_16x16x32_bf16(
                    af[mi], bfr[ni], acc[mi][ni], 0, 0, 0);
    }

#pragma unroll
    for (int ni = 0; ni < 4; ++ni) {
        int gcol = bn + wn + ni * 16 + (lane & 15);
        float bv = bias[gcol];
#pragma unroll
        for (int mi = 0; mi < 4; ++mi) {
#pragma unroll
            for (int q = 0; q < 4; ++q) {
                int grow = bm + wm + mi * 16 + ((lane >> 4) << 2) + q;
                float x = acc[mi][ni][q] + bv;
                if (RELU) x = fmaxf(x, 0.f);
                if (OUTBF16)
                    ((unsigned short*)Cout)[(size_t)grow * ldc + gcol] = bf16r(x);
                else
                    ((float*)Cout)[(size_t)grow * ldc + gcol] = x;
            }
        }
    }
}

// ---------------------------------------------------------------------------
// Fused log_softmax (in place on d_out) + CTC prob gather -> compact bf16 P,
// pre-boosted by 2^12 so the DP's alpha drifts upward (wide flush window).
// ---------------------------------------------------------------------------
__global__ __launch_bounds__(256) void lsm_gather(
    float* __restrict__ lp, const int* __restrict__ targets,
    unsigned short* __restrict__ P)
{
    const int w = (blockIdx.x << 2) + (threadIdx.x >> 6);
    const int l = threadIdx.x & 63;
    const int wl = threadIdx.x >> 6;
    const int b = w >> 11;

    float* row = lp + (size_t)w * 512;
    float4 v0 = ((const float4*)row)[l];
    float4 v1 = ((const float4*)row)[64 + l];
    float m = fmaxf(fmaxf(fmaxf(v0.x, v0.y), fmaxf(v0.z, v0.w)),
                    fmaxf(fmaxf(v1.x, v1.y), fmaxf(v1.z, v1.w)));
#pragma unroll
    for (int off = 1; off < 64; off <<= 1) m = fmaxf(m, __shfl_xor(m, off));
    float s = expf(v0.x - m) + expf(v0.y - m) + expf(v0.z - m) + expf(v0.w - m)
            + expf(v1.x - m) + expf(v1.y - m) + expf(v1.z - m) + expf(v1.w - m);
#pragma unroll
    for (int off = 1; off < 64; off <<= 1) s += __shfl_xor(s, off);
    float lse = m + logf(s);
    v0.x -= lse; v0.y -= lse; v0.z -= lse; v0.w -= lse;
    v1.x -= lse; v1.y -= lse; v1.z -= lse; v1.w -= lse;
    ((float4*)row)[l] = v0;
    ((float4*)row)[64 + l] = v1;

    __shared__ float pr[4][512];
    pr[wl][l * 4 + 0] = expf(v0.x) * BOOST; pr[wl][l * 4 + 1] = expf(v0.y) * BOOST;
    pr[wl][l * 4 + 2] = expf(v0.z) * BOOST; pr[wl][l * 4 + 3] = expf(v0.w) * BOOST;
    pr[wl][256 + l * 4 + 0] = expf(v1.x) * BOOST; pr[wl][256 + l * 4 + 1] = expf(v1.y) * BOOST;
    pr[wl][256 + l * 4 + 2] = expf(v1.z) * BOOST; pr[wl][256 + l * 4 + 3] = expf(v1.w) * BOOST;
    __syncthreads();

    int4 tg = ((const int4*)(targets + (size_t)b * L_))[l];
    ushort4 o;
    o.x = bf16r(pr[wl][tg.x]); o.y = bf16r(pr[wl][tg.y]);
    o.z = bf16r(pr[wl][tg.z]); o.w = bf16r(pr[wl][tg.w]);
    *(ushort4*)&P[(size_t)w * PSTRIDE + l * 4] = o;
    if (l == 0) P[(size_t)w * PSTRIDE + 256] = bf16r(pr[wl][BLANKI]);
}

// ---------------------------------------------------------------------------
// CTC DP, prob domain, boosted probs + deferred power-of-2 rescale.
// Window [2^-24, 2^96]: worst-case retained relative precision >= ~2^-89.
// 1 wave/sample; lane l owns states 8l..8l+7 (lane 63 also 512).
// ---------------------------------------------------------------------------
__global__ __launch_bounds__(64) void ctc_dp3(
    const unsigned short* __restrict__ P,
    const int* __restrict__ enc_mask, const int* __restrict__ targets,
    const int* __restrict__ tgt_mask,
    float* __restrict__ out_len_f, float* __restrict__ per_sample,
    int* __restrict__ tl_out)
{
    const int b = blockIdx.x;
    const int l = threadIdx.x;

    int se = 0, st = 0;
    {
        const int* em = enc_mask + (size_t)b * SSRC;
#pragma unroll
        for (int i = 0; i < 8; ++i) se += (em[i * 64 + l] != 0) ? 1 : 0;
        const int* tm = tgt_mask + (size_t)b * L_;
#pragma unroll
        for (int i = 0; i < 4; ++i) st += (tm[i * 64 + l] != 0) ? 1 : 0;
#pragma unroll
        for (int off = 32; off; off >>= 1) {
            se += __shfl_xor(se, off);
            st += __shfl_xor(st, off);
        }
    }
    const int tl = st;
    const int IL = STRIDE_ * se;

    const int4 tg = ((const int4*)(targets + (size_t)b * L_))[l];
    int prevw = __shfl_up(tg.w, 1);
    if (l == 0) prevw = BLANKI;
    const bool k1 = (tg.x != BLANKI) && (tg.x != prevw);
    const bool k3 = (tg.y != BLANKI) && (tg.y != tg.x);
    const bool k5 = (tg.z != BLANKI) && (tg.z != tg.y);
    const bool k7 = (tg.w != BLANKI) && (tg.w != tg.z);

    const unsigned short* Pb = P + (size_t)b * T_ * PSTRIDE;

    float a0 = 0, a1 = 0, a2 = 0, a3 = 0, a4 = 0, a5 = 0, a6 = 0, a7 = 0, a8 = 0;
    if (l == 0) {
        a0 = bf2f(Pb[256]);                 // boosted blank prob at t=0
        if (tl > 0) a1 = bf2f(Pb[0]);       // boosted first target prob at t=0
    }
    int Ei = 0;

    constexpr float HIc = 7.9228163e28f;    // 2^96
    constexpr float LOc = 5.9604645e-8f;    // 2^-24

    auto dostep = [&](ushort4 pq, unsigned short pbu) {
        float p1 = bf2f(pq.x), p3 = bf2f(pq.y), p5 = bf2f(pq.z), p7 = bf2f(pq.w);
        float pb = bf2f(pbu);
        float u1 = __shfl_up(a7, 1);
        if (l == 0) u1 = 0.f;
        float n0 = (a0 + u1) * pb;
        float n1 = (a1 + a0 + (k1 ? u1 : 0.f)) * p1;
        float n2 = (a2 + a1) * pb;
        float n3 = (a3 + a2 + (k3 ? a1 : 0.f)) * p3;
        float n4 = (a4 + a3) * pb;
        float n5 = (a5 + a4 + (k5 ? a3 : 0.f)) * p5;
        float n6 = (a6 + a5) * pb;
        float n7 = (a7 + a6 + (k7 ? a5 : 0.f)) * p7;
        float n8 = (l == 63) ? (a8 + a7) * pb : 0.f;
        float mloc = fmaxf(fmaxf(fmaxf(n0, n1), fmaxf(n2, n3)),
                           fmaxf(fmaxf(n4, n5), fmaxf(n6, n7)));
        mloc = fmaxf(mloc, n8);
        bool hi = mloc > HIc;
        bool lo = mloc < LOc;
        if (__any(hi) || __all(lo)) {
            float m = mloc;
#pragma unroll
            for (int off = 1; off < 64; off <<= 1) m = fmaxf(m, __shfl_xor(m, off));
            int eb = (int)((__float_as_uint(m) >> 23) & 0xffu) - 127;
            float sc = __uint_as_float((unsigned)(127 - eb) << 23);   // 2^-eb
            Ei += eb;
            n0 *= sc; n1 *= sc; n2 *= sc; n3 *= sc; n4 *= sc;
            n5 *= sc; n6 *= sc; n7 *= sc; n8 *= sc;
        }
        a0 = n0; a1 = n1; a2 = n2; a3 = n3; a4 = n4; a5 = n5; a6 = n6; a7 = n7; a8 = n8;
    };

    const int tmax = IL - 1;
    if (tmax >= 1) {
        ushort4 pv[8]; unsigned short pbv[8];
        auto ldrow = [&](int i, int t) {
            const unsigned short* rp = Pb + (size_t)t * PSTRIDE;
            pv[i] = *(const ushort4*)(rp + 4 * l);
            pbv[i] = rp[256];
        };
#pragma unroll
        for (int i = 0; i < 8; ++i) { int t0 = 1 + i; ldrow(i, t0 <= tmax ? t0 : tmax); }
        int t = 1;
        for (; t + 7 <= tmax; t += 8) {
#pragma unroll
            for (int i = 0; i < 8; ++i) {
                dostep(pv[i], pbv[i]);
                int tn = t + i + 8;
                if (tn <= tmax) ldrow(i, tn);
            }
        }
#pragma unroll
        for (int i = 0; i < 8; ++i)
            if (t + i <= tmax) dostep(pv[i], pbv[i]);
    }

    __shared__ float as_[S_];
    as_[l * 8 + 0] = a0; as_[l * 8 + 1] = a1; as_[l * 8 + 2] = a2; as_[l * 8 + 3] = a3;
    as_[l * 8 + 4] = a4; as_[l * 8 + 5] = a5; as_[l * 8 + 6] = a6; as_[l * 8 + 7] = a7;
    if (l == 63) as_[512] = a8;
    __syncthreads();
    if (l == 0) {
        int i2 = 2 * tl;
        float al = as_[i2];
        float ap = (tl > 0) ? as_[i2 - 1] : 0.f;
        float s = al + ap;
        // alpha_true = stored * 2^(Ei - BOOST_BITS*IL)
        per_sample[b] = -(logf(s) +
            (float)(Ei - BOOST_BITS * IL) * 0.69314718055994531f);
        tl_out[b] = tl;
        out_len_f[b] = (float)IL;
    }
}

__global__ __launch_bounds__(64) void ctc_loss_final(
    const float* __restrict__ per_sample, const int* __restrict__ tl,
    float* __restrict__ out_loss)
{
    int tid = threadIdx.x;
    float v = 0.f;
    if (tid < B_) {
        int t = tl[tid] < 1 ? 1 : tl[tid];
        v = per_sample[tid] / (float)t;
    }
#pragma unroll
    for (int off = 32; off; off >>= 1) v += __shfl_down(v, off);
    if (tid == 0) {
        float loss = v / (float)B_;
        if (isnan(loss) || isinf(loss)) loss = 0.f;
        *out_loss = loss;
    }
}

// ---------------------------------------------------------------------------
extern "C" void kernel_launch(void* const* d_in, const int* in_sizes, int n_in,
                              void* d_out, int out_size, void* d_ws, size_t ws_size,
                              hipStream_t stream)
{
    (void)in_sizes; (void)n_in; (void)out_size; (void)ws_size;

    const float* rep      = (const float*)d_in[0];
    const int*   enc_mask = (const int*)d_in[1];
    const int*   targets  = (const int*)d_in[2];
    const int*   tgt_mask = (const int*)d_in[3];
    const float* W_exp    = (const float*)d_in[4];
    const float* b_exp    = (const float*)d_in[5];
    const float* W1       = (const float*)d_in[6];
    const float* b1       = (const float*)d_in[7];
    const float* W2       = (const float*)d_in[8];
    const float* b2       = (const float*)d_in[9];

    float* out       = (float*)d_out;
    float* logprobs  = out;
    float* out_len_f = out + (size_t)B_ * T_ * V_;
    float* out_loss  = out_len_f + B_;

    // ws layout, 38.8 MB total:
    unsigned short* WcT = (unsigned short*)d_ws;                  // [4096][512] bf16
    float* bc           = (float*)(WcT + (size_t)4096 * 512);     // [4096]
    float* per_sample   = bc + 4096;                              // [64]
    int*   tl_out       = (int*)(per_sample + 64);                // [64]
    unsigned short* P   = (unsigned short*)(tl_out + 64);         // [65536][264] bf16
    // aliased inside the P region (all dead before lsm_gather writes P):
    float*          Wc_tmp = (float*)P;                           // [512][4096] f32
    unsigned short* Hc     = (unsigned short*)P;                  // [2048][4096] bf16
    unsigned short* repb   = Hc + (size_t)2048 * 4096;            // [16384][512]
    unsigned short* W2T    = repb + (size_t)16384 * 512;          // [512][1024]

    // 1) rep -> bf16
    cvt_f32_bf16<<<8192, 256, 0, stream>>>(rep, repb, (16384 * 512) / 4);

    // 2) fold: Wc[e, k*1024+h] = sum_d W_exp[e,k*512+d] * W1[d,h]
    gemm_f32z<<<dim3(8, 4, 4), 256, 0, stream>>>(
        W_exp, 2048, 512, W1, 1024, Wc_tmp, 4096, 1024, 512);
    combine_bias<<<16, 256, 0, stream>>>(b_exp, W1, b1, bc);

    // 3) bf16 transposed weights
    transpose_cvt<<<dim3(128, 16), dim3(32, 8), 0, stream>>>(Wc_tmp, WcT, 512, 4096);
    transpose_cvt<<<dim3(16, 32), dim3(32, 8), 0, stream>>>(W2, W2T, 1024, 512);

    // 4) 8 chunks: H = relu(rep@Wc+bc) bf16; logits = H@W2+b2 -> d_out f32
    for (int c = 0; c < 8; ++c) {
        gemm_mfma<true, true><<<dim3(32, 16), 256, 0, stream>>>(
            repb + (size_t)c * 2048 * 512, 512, WcT, 512, Hc, 4096, bc, 512);
        gemm_mfma<false, false><<<dim3(4, 64), 256, 0, stream>>>(
            Hc, 1024, W2T, 1024, logprobs + (size_t)c * 8192 * 512, 512, b2, 1024);
    }

    // 5) fused log_softmax (in place) + boosted prob gather -> P
    lsm_gather<<<(B_ * T_) / 4, 256, 0, stream>>>(logprobs, targets, P);

    // 6) CTC DP + loss
    ctc_dp3<<<B_, 64, 0, stream>>>(P, enc_mask, targets, tgt_mask,
                                   out_len_f, per_sample, tl_out);
    ctc_loss_final<<<1, 64, 0, stream>>>(per_sample, tl_out, out_loss);
}

// Round 7
// 694.832 us; speedup vs baseline: 4.7896x; 1.2761x over previous
//
#include <hip/hip_runtime.h>
#include <math.h>

#define B_ 32
#define SSRC 512
#define D_ 512
#define STRIDE_ 4
#define V_ 512
#define L_ 256
#define T_ (SSRC * STRIDE_)   // 2048
#define S_ (2 * L_ + 1)       // 513
#define BLANKI 1
#define PSTRIDE 264           // compact prob row stride (ushorts)
#define BOOST 4096.0f         // 2^12 pre-boost on gathered probs
#define BOOST_BITS 12

typedef __attribute__((ext_vector_type(8))) short bf16x8;
typedef __attribute__((ext_vector_type(4))) float f32x4;

__device__ __forceinline__ unsigned short bf16r(float x) {
    unsigned u = __float_as_uint(x);
    return (unsigned short)((u + 0x7fffu + ((u >> 16) & 1u)) >> 16);
}
__device__ __forceinline__ float bf2f(unsigned short u) {
    return __uint_as_float((unsigned)u << 16);
}
__device__ __forceinline__ void gl_lds16(const unsigned short* g, unsigned short* l) {
    __builtin_amdgcn_global_load_lds(
        (const __attribute__((address_space(1))) unsigned int*)g,
        (__attribute__((address_space(3))) unsigned int*)l, 16, 0, 0);
}

// ---------------------------------------------------------------------------
// fp32 tiled GEMM for the weight fold (gridDim.z slices). BM=BN=128, BK=8.
// ---------------------------------------------------------------------------
__global__ __launch_bounds__(256) void gemm_f32z(
    const float* __restrict__ A, int lda, int zA,
    const float* __restrict__ Bm, int ldb,
    float* __restrict__ C, int ldc, int zC, int K)
{
    constexpr int BK = 8;
    __shared__ float As[BK][128];
    __shared__ float Bs[BK][128];
    A += (size_t)blockIdx.z * zA;
    C += (size_t)blockIdx.z * zC;
    const int tid = threadIdx.x;
    const long bm = (long)blockIdx.y * 128;
    const long bn = (long)blockIdx.x * 128;
    const int tx = tid & 15, ty = tid >> 4;
    float acc[8][8] = {};
    const int arow = tid >> 1, acol = (tid & 1) << 2;
    const int brow = tid >> 5, bcol = (tid & 31) << 2;
    const float* Ap = A + (bm + arow) * (long)lda + acol;
    const float* Bp = Bm + (long)brow * ldb + bn + bcol;
    for (int k0 = 0; k0 < K; k0 += BK) {
        float4 av = *(const float4*)Ap;
        float4 bv = *(const float4*)Bp;
        __syncthreads();
        As[acol + 0][arow] = av.x; As[acol + 1][arow] = av.y;
        As[acol + 2][arow] = av.z; As[acol + 3][arow] = av.w;
        *(float4*)&Bs[brow][bcol] = bv;
        __syncthreads();
        Ap += BK; Bp += (long)BK * ldb;
#pragma unroll
        for (int k = 0; k < BK; ++k) {
            float a[8], b[8];
            *(float4*)&a[0] = *(const float4*)&As[k][ty * 8];
            *(float4*)&a[4] = *(const float4*)&As[k][ty * 8 + 4];
            *(float4*)&b[0] = *(const float4*)&Bs[k][tx * 4];
            *(float4*)&b[4] = *(const float4*)&Bs[k][tx * 4 + 64];
#pragma unroll
            for (int i = 0; i < 8; ++i)
#pragma unroll
                for (int j = 0; j < 8; ++j)
                    acc[i][j] = fmaf(a[i], b[j], acc[i][j]);
        }
    }
#pragma unroll
    for (int i = 0; i < 8; ++i) {
        long row = bm + ty * 8 + i;
        float* crow = C + row * (long)ldc + bn;
        *(float4*)&crow[tx * 4]      = make_float4(acc[i][0], acc[i][1], acc[i][2], acc[i][3]);
        *(float4*)&crow[64 + tx * 4] = make_float4(acc[i][4], acc[i][5], acc[i][6], acc[i][7]);
    }
}

// ---------------------------------------------------------------------------
__global__ __launch_bounds__(256) void combine_bias(
    const float* __restrict__ b_exp, const float* __restrict__ W1,
    const float* __restrict__ b1, float* __restrict__ bc)
{
    int j = blockIdx.x * 256 + threadIdx.x;
    int k = j >> 10, h = j & 1023;
    float s = b1[h];
    const float* be = b_exp + k * 512;
    for (int d = 0; d < 512; ++d)
        s = fmaf(be[d], W1[d * 1024 + h], s);
    bc[j] = s;
}

// ---------------------------------------------------------------------------
__global__ __launch_bounds__(256) void transpose_cvt(
    const float* __restrict__ in, unsigned short* __restrict__ out, int R, int C)
{
    __shared__ float tile[32][33];
    int bx = blockIdx.x * 32, by = blockIdx.y * 32;
    int tx = threadIdx.x, ty = threadIdx.y;
#pragma unroll
    for (int i = 0; i < 32; i += 8)
        tile[ty + i][tx] = in[(size_t)(by + ty + i) * C + bx + tx];
    __syncthreads();
#pragma unroll
    for (int i = 0; i < 32; i += 8)
        out[(size_t)(bx + ty + i) * R + by + tx] = bf16r(tile[tx][ty + i]);
}

__global__ __launch_bounds__(256) void cvt_f32_bf16(
    const float* __restrict__ in, unsigned short* __restrict__ out, int n4)
{
    int i = blockIdx.x * 256 + threadIdx.x;
    if (i >= n4) return;
    float4 v = ((const float4*)in)[i];
    ushort4 o;
    o.x = bf16r(v.x); o.y = bf16r(v.y); o.z = bf16r(v.z); o.w = bf16r(v.w);
    ((ushort4*)out)[i] = o;
}

// ---------------------------------------------------------------------------
// bf16 MFMA GEMM (m97 structure) + bijective XCD swizzle (nwg % 8 == 0).
// ---------------------------------------------------------------------------
template <bool RELU, bool OUTBF16>
__global__ __launch_bounds__(256) void gemm_mfma(
    const unsigned short* __restrict__ A, int lda,
    const unsigned short* __restrict__ BT, int ldb,
    void* __restrict__ Cout, int ldc,
    const float* __restrict__ bias, int K)
{
    __shared__ unsigned short As[2][128][32];
    __shared__ unsigned short Bs[2][128][32];
    const int tid = threadIdx.x;
    const int wid = tid >> 6, lane = tid & 63;

    // XCD-aware swizzle of the flattened block index (nwg divisible by 8)
    const int gx = gridDim.x;
    int wg = blockIdx.y * gx + blockIdx.x;
    const int q = (gx * gridDim.y) >> 3;
    wg = (wg & 7) * q + (wg >> 3);
    const int bm = (wg / gx) * 128, bn = (wg % gx) * 128;

    const int wm = (wid >> 1) * 64, wn = (wid & 1) * 64;

    f32x4 acc[4][4] = {};
    const int r_in = lane >> 2;
    const int cch = (lane & 3) * 8;
    const int rbase = wid * 32;

    auto stage = [&](int buf, int k0) {
#pragma unroll
        for (int i = 0; i < 2; ++i) {
            int rloc = rbase + i * 16;
            gl_lds16(A  + (size_t)(bm + rloc + r_in) * lda + k0 + cch, &As[buf][rloc][0]);
            gl_lds16(BT + (size_t)(bn + rloc + r_in) * ldb + k0 + cch, &Bs[buf][rloc][0]);
        }
    };

    const int nt = K / 32;
    stage(0, 0);
    for (int t = 0; t < nt; ++t) {
        int cur = t & 1;
        __syncthreads();
        if (t + 1 < nt) stage(cur ^ 1, (t + 1) * 32);
        bf16x8 af[4], bfr[4];
#pragma unroll
        for (int mi = 0; mi < 4; ++mi)
            af[mi] = *(const bf16x8*)&As[cur][wm + mi * 16 + (lane & 15)][(lane >> 4) * 8];
#pragma unroll
        for (int ni = 0; ni < 4; ++ni)
            bfr[ni] = *(const bf16x8*)&Bs[cur][wn + ni * 16 + (lane & 15)][(lane >> 4) * 8];
#pragma unroll
        for (int mi = 0; mi < 4; ++mi)
#pragma unroll
            for (int ni = 0; ni < 4; ++ni)
                acc[mi][ni] = __builtin_amdgcn_mfma_f32_16x16x32_bf16(
                    af[mi], bfr[ni], acc[mi][ni], 0, 0, 0);
    }

#pragma unroll
    for (int ni = 0; ni < 4; ++ni) {
        int gcol = bn + wn + ni * 16 + (lane & 15);
        float bv = bias[gcol];
#pragma unroll
        for (int mi = 0; mi < 4; ++mi) {
#pragma unroll
            for (int q2 = 0; q2 < 4; ++q2) {
                int grow = bm + wm + mi * 16 + ((lane >> 4) << 2) + q2;
                float x = acc[mi][ni][q2] + bv;
                if (RELU) x = fmaxf(x, 0.f);
                if (OUTBF16)
                    ((unsigned short*)Cout)[(size_t)grow * ldc + gcol] = bf16r(x);
                else
                    ((float*)Cout)[(size_t)grow * ldc + gcol] = x;
            }
        }
    }
}

// ---------------------------------------------------------------------------
// Fused log_softmax (in place) + boosted prob gather -> compact bf16 P.
// ---------------------------------------------------------------------------
__global__ __launch_bounds__(256) void lsm_gather(
    float* __restrict__ lp, const int* __restrict__ targets,
    unsigned short* __restrict__ P)
{
    const int w = (blockIdx.x << 2) + (threadIdx.x >> 6);
    const int l = threadIdx.x & 63;
    const int wl = threadIdx.x >> 6;
    const int b = w >> 11;

    float* row = lp + (size_t)w * 512;
    float4 v0 = ((const float4*)row)[l];
    float4 v1 = ((const float4*)row)[64 + l];
    float m = fmaxf(fmaxf(fmaxf(v0.x, v0.y), fmaxf(v0.z, v0.w)),
                    fmaxf(fmaxf(v1.x, v1.y), fmaxf(v1.z, v1.w)));
#pragma unroll
    for (int off = 1; off < 64; off <<= 1) m = fmaxf(m, __shfl_xor(m, off));
    float e0 = expf(v0.x - m), e1 = expf(v0.y - m), e2 = expf(v0.z - m), e3 = expf(v0.w - m);
    float e4 = expf(v1.x - m), e5 = expf(v1.y - m), e6 = expf(v1.z - m), e7 = expf(v1.w - m);
    float s = (e0 + e1) + (e2 + e3) + (e4 + e5) + (e6 + e7);
#pragma unroll
    for (int off = 1; off < 64; off <<= 1) s += __shfl_xor(s, off);
    float lse = m + logf(s);
    v0.x -= lse; v0.y -= lse; v0.z -= lse; v0.w -= lse;
    v1.x -= lse; v1.y -= lse; v1.z -= lse; v1.w -= lse;
    ((float4*)row)[l] = v0;
    ((float4*)row)[64 + l] = v1;

    const float Cf = BOOST / s;   // exp(v - lse)*BOOST = e_j * BOOST / s
    __shared__ float pr[4][512];
    pr[wl][l * 4 + 0] = e0 * Cf; pr[wl][l * 4 + 1] = e1 * Cf;
    pr[wl][l * 4 + 2] = e2 * Cf; pr[wl][l * 4 + 3] = e3 * Cf;
    pr[wl][256 + l * 4 + 0] = e4 * Cf; pr[wl][256 + l * 4 + 1] = e5 * Cf;
    pr[wl][256 + l * 4 + 2] = e6 * Cf; pr[wl][256 + l * 4 + 3] = e7 * Cf;
    __syncthreads();

    int4 tg = ((const int4*)(targets + (size_t)b * L_))[l];
    ushort4 o;
    o.x = bf16r(pr[wl][tg.x]); o.y = bf16r(pr[wl][tg.y]);
    o.z = bf16r(pr[wl][tg.z]); o.w = bf16r(pr[wl][tg.w]);
    *(ushort4*)&P[(size_t)w * PSTRIDE + l * 4] = o;
    if (l == 0) P[(size_t)w * PSTRIDE + 256] = bf16r(pr[wl][BLANKI]);
}

// ---------------------------------------------------------------------------
// CTC forward/backward DP split, f64 accumulators.
// blocks 0..31 = forward to t=h; blocks 32..63 = backward down to h.
// f64 window (+-1022 bits) makes stored-support disjointness at the meeting
// point impossible (the R6 f32 failure). Unconditional rescale every 16 steps
// via int-exponent butterfly (growth <= 2^218 per 16 steps, no overflow).
// Lane l owns states 8l..8l+7; lane 63 also state 512.
// ---------------------------------------------------------------------------
struct Pr5 { float pb, p1, p3, p5, p7; };

__device__ __forceinline__ Pr5 ldrowf(const unsigned short* rp, int l)
{
    ushort4 q = *(const ushort4*)(rp + 4 * l);
    Pr5 r;
    r.pb = bf2f(rp[256]);
    r.p1 = bf2f(q.x); r.p3 = bf2f(q.y); r.p5 = bf2f(q.z); r.p7 = bf2f(q.w);
    return r;
}

__global__ __launch_bounds__(64) void ctc_fwd_bwd(
    const unsigned short* __restrict__ P,
    const int* __restrict__ enc_mask, const int* __restrict__ targets,
    const int* __restrict__ tgt_mask,
    float* __restrict__ out_len_f,
    double* __restrict__ AV, double* __restrict__ BV,
    int* __restrict__ EF, int* __restrict__ EB,
    int* __restrict__ ILv, int* __restrict__ tl_out)
{
    const int b = blockIdx.x & 31;
    const bool isf = blockIdx.x < 32;
    const int l = threadIdx.x;

    int se = 0, st = 0;
    {
        const int* em = enc_mask + (size_t)b * SSRC;
#pragma unroll
        for (int i = 0; i < 8; ++i) se += (em[i * 64 + l] != 0) ? 1 : 0;
        const int* tm = tgt_mask + (size_t)b * L_;
#pragma unroll
        for (int i = 0; i < 4; ++i) st += (tm[i * 64 + l] != 0) ? 1 : 0;
#pragma unroll
        for (int off = 32; off; off >>= 1) {
            se += __shfl_xor(se, off);
            st += __shfl_xor(st, off);
        }
    }
    const int tl = st;
    const int IL = STRIDE_ * se;
    const int h = (IL > 0) ? ((IL - 1) >> 1) : 0;

    const int4 tg = ((const int4*)(targets + (size_t)b * L_))[l];
    int prevw = __shfl_up(tg.w, 1);
    if (l == 0) prevw = BLANKI;
    const bool k1 = (tg.x != BLANKI) && (tg.x != prevw);
    const bool k3 = (tg.y != BLANKI) && (tg.y != tg.x);
    const bool k5 = (tg.z != BLANKI) && (tg.z != tg.y);
    const bool k7 = (tg.w != BLANKI) && (tg.w != tg.z);

    const unsigned short* Pb = P + (size_t)b * T_ * PSTRIDE;

    double a0 = 0, a1 = 0, a2 = 0, a3 = 0, a4 = 0, a5 = 0, a6 = 0, a7 = 0, a8 = 0;
    int Ei = 0;

    // wave-uniform power-of-2 rescale: extract max f64 exponent, butterfly on int
    auto rescale9 = [&]() {
        double m = fmax(fmax(fmax(a0, a1), fmax(a2, a3)),
                        fmax(fmax(a4, a5), fmax(fmax(a6, a7), a8)));
        int e = (int)((__double_as_longlong(m) >> 52) & 0x7ff);
#pragma unroll
        for (int off = 1; off < 64; off <<= 1) {
            int o = __shfl_xor(e, off);
            e = o > e ? o : e;
        }
        int sh = 1023 - e;                    // scale = 2^sh, sh in [-1023, 1023]
        double sc = __longlong_as_double(((long long)(sh + 1023)) << 52);
        Ei += e - 1023;
        a0 *= sc; a1 *= sc; a2 *= sc; a3 *= sc; a4 *= sc;
        a5 *= sc; a6 *= sc; a7 *= sc; a8 *= sc;
    };

    if (isf) {
        // ---- forward: init t=0, steps t=1..h ----
        if (l == 0) {
            a0 = (double)bf2f(Pb[256]);
            if (tl > 0) a1 = (double)bf2f(Pb[0]);
        }
        auto fstep = [&](const Pr5& r) {
            double pb = (double)r.pb, p1 = (double)r.p1, p3 = (double)r.p3;
            double p5 = (double)r.p5, p7 = (double)r.p7;
            double u1 = __shfl_up(a7, 1);
            if (l == 0) u1 = 0.0;
            double n0 = (a0 + u1) * pb;
            double n1 = (a0 + a1 + (k1 ? u1 : 0.0)) * p1;
            double n2 = (a1 + a2) * pb;
            double n3 = (a2 + a3 + (k3 ? a1 : 0.0)) * p3;
            double n4 = (a3 + a4) * pb;
            double n5 = (a4 + a5 + (k5 ? a3 : 0.0)) * p5;
            double n6 = (a5 + a6) * pb;
            double n7 = (a6 + a7 + (k7 ? a5 : 0.0)) * p7;
            double n8 = (l == 63) ? (a7 + a8) * pb : 0.0;
            a0 = n0; a1 = n1; a2 = n2; a3 = n3; a4 = n4;
            a5 = n5; a6 = n6; a7 = n7; a8 = n8;
        };
        const int nst = h;
        if (nst > 0) {
            Pr5 ring[8];
#pragma unroll
            for (int i = 0; i < 8; ++i) {
                int ti = 1 + i; if (ti > nst) ti = nst;
                ring[i] = ldrowf(Pb + (size_t)ti * PSTRIDE, l);
            }
            int t = 1;
            const int nblk = nst >> 3;
            for (int blk = 0; blk < nblk; ++blk) {
#pragma unroll
                for (int i = 0; i < 8; ++i) {
                    fstep(ring[i]);
                    int tn = t + 8; if (tn > nst) tn = nst;
                    ring[i] = ldrowf(Pb + (size_t)tn * PSTRIDE, l);
                    ++t;
                }
                if (blk & 1) rescale9();
            }
            const int rem = nst & 7;
            for (int i = 0; i < rem; ++i) fstep(ring[i]);
        }
        rescale9();
        double* av = AV + b * 520;
        av[l * 8 + 0] = a0; av[l * 8 + 1] = a1; av[l * 8 + 2] = a2; av[l * 8 + 3] = a3;
        av[l * 8 + 4] = a4; av[l * 8 + 5] = a5; av[l * 8 + 6] = a6; av[l * 8 + 7] = a7;
        if (l == 63) av[512] = a8;
        if (l == 0) {
            EF[b] = Ei; ILv[b] = IL; tl_out[b] = tl;
            out_len_f[b] = (float)IL;
        }
    } else {
        // ---- backward: init t=IL-1, steps consuming rows IL-1 .. h+1 ----
        {
            int s0 = l * 8;
            int e0 = 2 * tl, e1 = 2 * tl - 1;
            a0 = (s0 + 0 == e0 || (tl > 0 && s0 + 0 == e1)) ? 1.0 : 0.0;
            a1 = (s0 + 1 == e0 || (tl > 0 && s0 + 1 == e1)) ? 1.0 : 0.0;
            a2 = (s0 + 2 == e0 || (tl > 0 && s0 + 2 == e1)) ? 1.0 : 0.0;
            a3 = (s0 + 3 == e0 || (tl > 0 && s0 + 3 == e1)) ? 1.0 : 0.0;
            a4 = (s0 + 4 == e0 || (tl > 0 && s0 + 4 == e1)) ? 1.0 : 0.0;
            a5 = (s0 + 5 == e0 || (tl > 0 && s0 + 5 == e1)) ? 1.0 : 0.0;
            a6 = (s0 + 6 == e0 || (tl > 0 && s0 + 6 == e1)) ? 1.0 : 0.0;
            a7 = (s0 + 7 == e0 || (tl > 0 && s0 + 7 == e1)) ? 1.0 : 0.0;
            if (l == 63) a8 = (512 == e0) ? 1.0 : 0.0;
        }
        float knff = __shfl_down(k1 ? 1.f : 0.f, 1);
        if (l == 63) knff = 0.f;
        const double knf = (double)knff;
        auto bstep = [&](const Pr5& r) {
            double pb = (double)r.pb, p1 = (double)r.p1, p3 = (double)r.p3;
            double p5 = (double)r.p5, p7 = (double)r.p7;
            double g0 = a0 * pb, g1 = a1 * p1, g2 = a2 * pb, g3 = a3 * p3;
            double g4 = a4 * pb, g5 = a5 * p5, g6 = a6 * pb, g7 = a7 * p7;
            double g8 = (l == 63) ? a8 * pb : 0.0;
            double d1 = __shfl_down(g0, 1);
            double d2 = __shfl_down(g1, 1);
            if (l == 63) { d1 = g8; d2 = 0.0; }
            double m0 = g0 + g1;
            double m1 = g1 + g2 + (k3 ? g3 : 0.0);
            double m2 = g2 + g3;
            double m3 = g3 + g4 + (k5 ? g5 : 0.0);
            double m4 = g4 + g5;
            double m5 = g5 + g6 + (k7 ? g7 : 0.0);
            double m6 = g6 + g7;
            double m7 = g7 + d1 + knf * d2;
            double m8 = (l == 63) ? g8 : 0.0;
            a0 = m0; a1 = m1; a2 = m2; a3 = m3; a4 = m4;
            a5 = m5; a6 = m6; a7 = m7; a8 = m8;
        };
        const int nbs = IL - 1 - h;     // rows IL-1 down to h+1
        if (nbs > 0) {
            const int rmin = h + 1;
            Pr5 ring[8];
#pragma unroll
            for (int i = 0; i < 8; ++i) {
                int ri = IL - 1 - i; if (ri < rmin) ri = rmin;
                ring[i] = ldrowf(Pb + (size_t)ri * PSTRIDE, l);
            }
            int gi = 0;
            const int nblk = nbs >> 3;
            for (int blk = 0; blk < nblk; ++blk) {
#pragma unroll
                for (int i = 0; i < 8; ++i) {
                    bstep(ring[i]);
                    int rn = IL - 1 - (gi + 8); if (rn < rmin) rn = rmin;
                    ring[i] = ldrowf(Pb + (size_t)rn * PSTRIDE, l);
                    ++gi;
                }
                if (blk & 1) rescale9();
            }
            const int rem = nbs & 7;
            for (int i = 0; i < rem; ++i) bstep(ring[i]);
        }
        rescale9();
        double* bv = BV + b * 520;
        bv[l * 8 + 0] = a0; bv[l * 8 + 1] = a1; bv[l * 8 + 2] = a2; bv[l * 8 + 3] = a3;
        bv[l * 8 + 4] = a4; bv[l * 8 + 5] = a5; bv[l * 8 + 6] = a6; bv[l * 8 + 7] = a7;
        if (l == 63) bv[512] = a8;
        if (l == 0) EB[b] = Ei;
    }
}

// ---------------------------------------------------------------------------
// f64 combine: Z = sum_s av[s]*bv[s] (no underflow possible in f64 -- each
// stored side is max-normalized, products >= 2^-2044 only if contributing).
// ---------------------------------------------------------------------------
__global__ __launch_bounds__(64) void ctc_combine(
    const double* __restrict__ AV, const double* __restrict__ BV,
    const int* __restrict__ EF, const int* __restrict__ EB,
    const int* __restrict__ ILv, float* __restrict__ per_sample)
{
    const int b = blockIdx.x, l = threadIdx.x;
    const double* av = AV + b * 520;
    const double* bv = BV + b * 520;
    double s = 0.0;
#pragma unroll
    for (int i = 0; i < 8; ++i)
        s += av[l * 8 + i] * bv[l * 8 + i];
    if (l == 63) s += av[512] * bv[512];
#pragma unroll
    for (int off = 1; off < 64; off <<= 1) s += __shfl_xor(s, off);
    if (l == 0) {
        double lg = log(s) +
            (double)(EF[b] + EB[b] - BOOST_BITS * ILv[b]) * 0.6931471805599453;
        per_sample[b] = -(float)lg;
    }
}

__global__ __launch_bounds__(64) void ctc_loss_final(
    const float* __restrict__ per_sample, const int* __restrict__ tl,
    float* __restrict__ out_loss)
{
    int tid = threadIdx.x;
    float v = 0.f;
    if (tid < B_) {
        int t = tl[tid] < 1 ? 1 : tl[tid];
        v = per_sample[tid] / (float)t;
    }
#pragma unroll
    for (int off = 32; off; off >>= 1) v += __shfl_down(v, off);
    if (tid == 0) {
        float loss = v / (float)B_;
        if (isnan(loss) || isinf(loss)) loss = 0.f;
        *out_loss = loss;
    }
}

// ---------------------------------------------------------------------------
extern "C" void kernel_launch(void* const* d_in, const int* in_sizes, int n_in,
                              void* d_out, int out_size, void* d_ws, size_t ws_size,
                              hipStream_t stream)
{
    (void)in_sizes; (void)n_in; (void)out_size; (void)ws_size;

    const float* rep      = (const float*)d_in[0];
    const int*   enc_mask = (const int*)d_in[1];
    const int*   targets  = (const int*)d_in[2];
    const int*   tgt_mask = (const int*)d_in[3];
    const float* W_exp    = (const float*)d_in[4];
    const float* b_exp    = (const float*)d_in[5];
    const float* W1       = (const float*)d_in[6];
    const float* b1       = (const float*)d_in[7];
    const float* W2       = (const float*)d_in[8];
    const float* b2       = (const float*)d_in[9];

    float* out       = (float*)d_out;
    float* logprobs  = out;
    float* out_len_f = out + (size_t)B_ * T_ * V_;
    float* out_loss  = out_len_f + B_;

    // ws layout (~39.2 MB total):
    unsigned short* WcT = (unsigned short*)d_ws;                  // [4096][512] bf16, 4 MB
    float* bc           = (float*)(WcT + (size_t)4096 * 512);     // [4096]
    float* per_sample   = bc + 4096;                              // [64]
    int*   tl_out       = (int*)(per_sample + 64);                // [64]
    unsigned short* P   = (unsigned short*)(tl_out + 64);         // [65536][264] bf16, 34.6 MB
    double* AV          = (double*)(P + (size_t)65536 * PSTRIDE); // [32][520] f64
    double* BV          = AV + 32 * 520;                          // [32][520] f64
    int*   EF           = (int*)(BV + 32 * 520);                  // [32]
    int*   EB           = EF + 32;                                // [32]
    int*   ILv          = EB + 32;                                // [32]
    // aliased inside the P region (dead before lsm_gather writes P):
    float*          Wc_tmp = (float*)P;                           // [512][4096] f32
    unsigned short* Hc     = (unsigned short*)P;                  // [2048][4096] bf16
    unsigned short* repb   = Hc + (size_t)2048 * 4096;            // [16384][512]
    unsigned short* W2T    = repb + (size_t)16384 * 512;          // [512][1024]

    // 1) rep -> bf16
    cvt_f32_bf16<<<8192, 256, 0, stream>>>(rep, repb, (16384 * 512) / 4);

    // 2) fold: Wc[e, k*1024+h] = sum_d W_exp[e,k*512+d] * W1[d,h]
    gemm_f32z<<<dim3(8, 4, 4), 256, 0, stream>>>(
        W_exp, 2048, 512, W1, 1024, Wc_tmp, 4096, 1024, 512);
    combine_bias<<<16, 256, 0, stream>>>(b_exp, W1, b1, bc);

    // 3) bf16 transposed weights
    transpose_cvt<<<dim3(128, 16), dim3(32, 8), 0, stream>>>(Wc_tmp, WcT, 512, 4096);
    transpose_cvt<<<dim3(16, 32), dim3(32, 8), 0, stream>>>(W2, W2T, 1024, 512);

    // 4) 8 chunks: H = relu(rep@Wc+bc) bf16; logits = H@W2+b2 -> d_out f32
    for (int c = 0; c < 8; ++c) {
        gemm_mfma<true, true><<<dim3(32, 16), 256, 0, stream>>>(
            repb + (size_t)c * 2048 * 512, 512, WcT, 512, Hc, 4096, bc, 512);
        gemm_mfma<false, false><<<dim3(4, 64), 256, 0, stream>>>(
            Hc, 1024, W2T, 1024, logprobs + (size_t)c * 8192 * 512, 512, b2, 1024);
    }

    // 5) fused log_softmax + boosted prob gather -> P
    lsm_gather<<<(B_ * T_) / 4, 256, 0, stream>>>(logprobs, targets, P);

    // 6) CTC DP: fwd (blocks 0-31) + bwd (blocks 32-63), then combine + loss
    ctc_fwd_bwd<<<64, 64, 0, stream>>>(P, enc_mask, targets, tgt_mask,
                                       out_len_f, AV, BV, EF, EB, ILv, tl_out);
    ctc_combine<<<32, 64, 0, stream>>>(AV, BV, EF, EB, ILv, per_sample);
    ctc_loss_final<<<1, 64, 0, stream>>>(per_sample, tl_out, out_loss);
}